// Round 19
// baseline (321.685 us; speedup 1.0000x reference)
//
#include <hip/hip_runtime.h>
#include <hip/hip_bf16.h>

// Qwen2VL vision block, MI355X gfx950.
// R19: combination pick — QKV stays gemmU (R18, helped total); FC1 reverts to
//      gemmS (measured best 85us vs gemmU 102us; waves/CU=24 beats 16).
//      proj/FC2 stay gemmS direct. Attention unchanged.

typedef __bf16 bf16_t;
typedef bf16_t bf16x8 __attribute__((ext_vector_type(8)));
typedef bf16_t bf16x4 __attribute__((ext_vector_type(4)));
typedef float f32x4 __attribute__((ext_vector_type(4)));

#define DIM 1280
#define NHEADS 16
#define HDIM 80
#define MLP 5120
#define NTOK 4096
#define QKV_N 3840

#define GLOAD_LDS16(gp, lp)                                                          \
    __builtin_amdgcn_global_load_lds((const __attribute__((address_space(1))) void*)(gp), \
                                     (__attribute__((address_space(3))) void*)(lp), 16, 0, 0)

// ---------------- fused fp32 -> bf16 conversion of all 4 weight tensors ------
__global__ void cvt_all(const float* __restrict__ s0, const float* __restrict__ s1,
                        const float* __restrict__ s2, const float* __restrict__ s3,
                        bf16_t* __restrict__ d0, bf16_t* __restrict__ d1,
                        bf16_t* __restrict__ d2, bf16_t* __restrict__ d3,
                        int n0, int n1, int n2, int n3) {
    int q0 = n0 >> 2, q1 = n1 >> 2, q2 = n2 >> 2, q3 = n3 >> 2;
    int total = q0 + q1 + q2 + q3;
    for (int i = blockIdx.x * blockDim.x + threadIdx.x; i < total;
         i += gridDim.x * blockDim.x) {
        const float* src;
        bf16_t* dst;
        int j = i;
        if (j < q0) { src = s0; dst = d0; }
        else if ((j -= q0) < q1) { src = s1; dst = d1; }
        else if ((j -= q1) < q2) { src = s2; dst = d2; }
        else { j -= q2; src = s3; dst = d3; }
        float4 v = ((const float4*)src)[j];
        bf16x4 o;
        o[0] = (bf16_t)v.x; o[1] = (bf16_t)v.y; o[2] = (bf16_t)v.z; o[3] = (bf16_t)v.w;
        *(bf16x4*)(dst + j * 4) = o;
    }
}

// ---------------- LayerNorm (fp32 in, bf16 out) ----------------
__global__ __launch_bounds__(256) void ln_kernel(const float* __restrict__ x,
                                                 const float* __restrict__ w,
                                                 const float* __restrict__ b,
                                                 bf16_t* __restrict__ out) {
    int row = blockIdx.x;
    const float* xr = x + (long)row * DIM;
    float v[5];
    float s = 0.f, ss = 0.f;
#pragma unroll
    for (int j = 0; j < 5; j++) {
        v[j] = xr[j * 256 + threadIdx.x];
        s += v[j];
        ss += v[j] * v[j];
    }
#pragma unroll
    for (int off = 32; off > 0; off >>= 1) {
        s += __shfl_xor(s, off, 64);
        ss += __shfl_xor(ss, off, 64);
    }
    __shared__ float red[8];
    int wid = threadIdx.x >> 6;
    if ((threadIdx.x & 63) == 0) { red[wid] = s; red[wid + 4] = ss; }
    __syncthreads();
    s = red[0] + red[1] + red[2] + red[3];
    ss = red[4] + red[5] + red[6] + red[7];
    float mean = s * (1.f / DIM);
    float var = ss * (1.f / DIM) - mean * mean;
    float rstd = rsqrtf(var + 1e-6f);
    bf16_t* orow = out + (long)row * DIM;
#pragma unroll
    for (int j = 0; j < 5; j++) {
        int d = j * 256 + threadIdx.x;
        orow[d] = (bf16_t)((v[j] - mean) * rstd * w[d] + b[d]);
    }
}

// ---------------- prep: fused RoPE + layouts; Q pre-scaled by scale*log2e ----
__global__ __launch_bounds__(256) void prep_kernel(const bf16_t* __restrict__ qkv,
                                                   const float* __restrict__ rot,
                                                   bf16_t* __restrict__ Qd,
                                                   bf16_t* __restrict__ Kd,
                                                   bf16_t* __restrict__ Vt) {
    const float SCL = 0.11180339887498949f * 1.4426950408889634f;  // 1/sqrt(80)*log2(e)
    __shared__ bf16_t tv[64 * 88];
    const int tid = threadIdx.x;
    const int t0 = blockIdx.x * 64;
    const int h = blockIdx.y;

    for (int c = tid; c < 64 * 10; c += 256) {
        int tl = c / 10, a = c % 10;
        bf16x8 v = *(const bf16x8*)(qkv + (long)(t0 + tl) * QKV_N + 2 * DIM + h * HDIM + a * 8);
        *(bf16x8*)(tv + tl * 88 + a * 8) = v;
    }

    for (int c = tid; c < 64 * 10; c += 256) {
        int tl = c / 10, a = c % 10;
        long gq = (long)(t0 + tl) * QKV_N + h * HDIM + a * 4;
        bf16x4 q1 = *(const bf16x4*)(qkv + gq);
        bf16x4 q2 = *(const bf16x4*)(qkv + gq + 40);
        bf16x4 k1 = *(const bf16x4*)(qkv + gq + DIM);
        bf16x4 k2 = *(const bf16x4*)(qkv + gq + DIM + 40);
        float4 rv = *(const float4*)(rot + (long)(t0 + tl) * 40 + a * 4);
        float rr[4] = {rv.x, rv.y, rv.z, rv.w};
        bf16x4 oq1, oq2, ok1, ok2;
#pragma unroll
        for (int j = 0; j < 4; j++) {
            float c_, s_;
            __sincosf(rr[j], &s_, &c_);
            float x1 = (float)q1[j], x2 = (float)q2[j];
            oq1[j] = (bf16_t)((x1 * c_ - x2 * s_) * SCL);
            oq2[j] = (bf16_t)((x2 * c_ + x1 * s_) * SCL);
            x1 = (float)k1[j]; x2 = (float)k2[j];
            ok1[j] = (bf16_t)(x1 * c_ - x2 * s_);
            ok2[j] = (bf16_t)(x2 * c_ + x1 * s_);
        }
        long o = ((long)h * NTOK + t0 + tl) * 96 + a * 4;
        *(bf16x4*)(Qd + o) = oq1;
        *(bf16x4*)(Qd + o + 40) = oq2;
        *(bf16x4*)(Kd + o) = ok1;
        *(bf16x4*)(Kd + o + 40) = ok2;
    }
    {
        bf16x8 z;
#pragma unroll
        for (int j = 0; j < 8; j++) z[j] = (bf16_t)0.f;
        for (int c = tid; c < 64 * 2; c += 256) {
            int tl = c / 2, a = c % 2;
            long o = ((long)h * NTOK + t0 + tl) * 96 + 80 + a * 8;
            *(bf16x8*)(Qd + o) = z;
            *(bf16x8*)(Kd + o) = z;
        }
    }
    __syncthreads();

    for (int c = tid; c < 80 * 8; c += 256) {
        int d = c / 8, tc = c % 8;
        bf16x8 v;
#pragma unroll
        for (int j = 0; j < 8; j++) v[j] = tv[(tc * 8 + j) * 88 + d];
        *(bf16x8*)(Vt + ((long)h * HDIM + d) * NTOK + t0 + tc * 8) = v;
    }
}

// ---------------- gemmU: 128(M) x 256(N), 8 waves, per-wave 64x64 (QKV) ------
template <int EPI>
__global__ __launch_bounds__(512, 2) void gemmU(const bf16_t* __restrict__ A,
                                                const bf16_t* __restrict__ B,
                                                const float* __restrict__ bias,
                                                void* __restrict__ Cv,
                                                int M, int N, int K) {
    __shared__ char lds[3 * 24576];  // 72 KB
    const int tid = threadIdx.x;
    const int lane = tid & 63;
    const int l15 = lane & 15;
    const int g = lane >> 4;
    const int wid = tid >> 6;   // 0..7
    const int wr = wid >> 2;    // 0..1 (M)
    const int wc = wid & 3;     // 0..3 (N)

    const int nx = gridDim.x;
    const int id = blockIdx.y * nx + blockIdx.x;
    const int cpx = (nx * gridDim.y) >> 3;
    const int sid = (id & 7) * cpx + (id >> 3);
    const int m0 = (sid / nx) * 128;
    const int n0 = (sid % nx) * 256;
    const int NT = K >> 5;

    const int soff = tid * 16;
    const int srow = soff >> 6;
    const int scb = (soff & 63) ^ (((srow >> 1) & 3) << 4);
    const bf16_t* g0 = A + (long)(m0 + srow) * K + (scb >> 1);
    const bf16_t* g1 = B + (long)(n0 + srow) * K + (scb >> 1);
    const int srow2 = 128 + srow;
    const int scb2 = (soff & 63) ^ (((srow2 >> 1) & 3) << 4);
    const bf16_t* g2 = B + (long)(n0 + srow2) * K + (scb2 >> 1);
    const int l0 = wid * 1024;
    const int l1 = 8192 + wid * 1024;
    const int l2 = 16384 + wid * 1024;

    f32x4 acc[4][4];
#pragma unroll
    for (int i = 0; i < 4; i++)
#pragma unroll
        for (int j = 0; j < 4; j++) acc[i][j] = (f32x4){0.f, 0.f, 0.f, 0.f};

    auto stage = [&](int buf, int t) {
        char* sb = lds + buf * 24576;
        GLOAD_LDS16(g0 + t * 32, sb + l0);
        GLOAD_LDS16(g1 + t * 32, sb + l1);
        GLOAD_LDS16(g2 + t * 32, sb + l2);
    };

    stage(0, 0);
    stage(1, 1);

    int buf = 0;
    for (int t = 0; t < NT; ++t) {
        if (t < NT - 1)
            asm volatile("s_waitcnt vmcnt(3)\n\ts_barrier" ::: "memory");
        else
            asm volatile("s_waitcnt vmcnt(0)\n\ts_barrier" ::: "memory");
        if (t + 2 < NT) stage((buf + 2) % 3, t + 2);

        const char* pA = lds + buf * 24576;
        const char* pB = pA + 8192;
        bf16x8 af[4], bb[4];
#pragma unroll
        for (int m = 0; m < 4; m++) {
            int r = wr * 64 + m * 16 + l15;
            af[m] = *(const bf16x8*)(pA + r * 64 + ((g * 16) ^ (((r >> 1) & 3) << 4)));
        }
#pragma unroll
        for (int n = 0; n < 4; n++) {
            int r = wc * 64 + n * 16 + l15;
            bb[n] = *(const bf16x8*)(pB + r * 64 + ((g * 16) ^ (((r >> 1) & 3) << 4)));
        }
        __builtin_amdgcn_s_setprio(1);
#pragma unroll
        for (int m = 0; m < 4; m++)
#pragma unroll
            for (int n = 0; n < 4; n++)
                acc[m][n] = __builtin_amdgcn_mfma_f32_16x16x32_bf16(af[m], bb[n],
                                                                    acc[m][n], 0, 0, 0);
        __builtin_amdgcn_s_setprio(0);
        buf = (buf + 1) % 3;
    }

#pragma unroll
    for (int m = 0; m < 4; m++)
#pragma unroll
        for (int n = 0; n < 4; n++) {
            const int col = n0 + wc * 64 + n * 16 + l15;
            const float bv = bias[col];
#pragma unroll
            for (int rr = 0; rr < 4; rr++) {
                const int row = m0 + wr * 64 + m * 16 + g * 4 + rr;
                const long idx = (long)row * N + col;
                float val = acc[m][n][rr] + bv;
                if (EPI == 0) {
                    ((bf16_t*)Cv)[idx] = (bf16_t)val;
                } else {
                    float ge = val / (1.f + __expf(-1.702f * val));
                    ((bf16_t*)Cv)[idx] = (bf16_t)ge;
                }
            }
        }
}

// ---------------- gemmS: 128x128, 8 waves 64x32, 24 waves/CU (proj/FC1/FC2) --
template <int EPI>
__global__ __launch_bounds__(512, 4) void gemmS(const bf16_t* __restrict__ A,
                                                const bf16_t* __restrict__ B,
                                                const float* __restrict__ bias,
                                                const float* __restrict__ res,
                                                void* __restrict__ Cv,
                                                int M, int N, int K, int kspl) {
    __shared__ char lds[3 * 16384];  // 48 KB
    const int tid = threadIdx.x;
    const int lane = tid & 63;
    const int l15 = lane & 15;
    const int g = lane >> 4;
    const int wid = tid >> 6;   // 0..7
    const int wr = wid >> 2;    // 0..1 (M)
    const int wc = wid & 3;     // 0..3 (N)

    const int nx = gridDim.x;
    const int id = blockIdx.y * nx + blockIdx.x;
    const int cpx = (nx * gridDim.y) >> 3;
    const int sid = (id & 7) * cpx + (id >> 3);
    const int m0 = (sid / nx) * 128;
    const int n0 = (sid % nx) * 128;
    const int k0 = blockIdx.z * kspl;
    const int NT = kspl >> 5;

    const int soff = tid * 16;
    const int srow = soff >> 6;
    const int scb = (soff & 63) ^ (((srow >> 1) & 3) << 4);
    const bf16_t* gA = A + (long)(m0 + srow) * K + k0 + (scb >> 1);
    const bf16_t* gB = B + (long)(n0 + srow) * K + k0 + (scb >> 1);
    const int lAo = wid * 1024;
    const int lBo = 8192 + wid * 1024;

    f32x4 acc[4][2];
#pragma unroll
    for (int i = 0; i < 4; i++)
#pragma unroll
        for (int j = 0; j < 2; j++) acc[i][j] = (f32x4){0.f, 0.f, 0.f, 0.f};

    auto stage = [&](int buf, int t) {
        char* sb = lds + buf * 16384;
        GLOAD_LDS16(gA + t * 32, sb + lAo);
        GLOAD_LDS16(gB + t * 32, sb + lBo);
    };

    stage(0, 0);
    stage(1, 1);

    int buf = 0;
    for (int t = 0; t < NT; ++t) {
        if (t < NT - 1)
            asm volatile("s_waitcnt vmcnt(2)\n\ts_barrier" ::: "memory");
        else
            asm volatile("s_waitcnt vmcnt(0)\n\ts_barrier" ::: "memory");
        if (t + 2 < NT) stage((buf + 2) % 3, t + 2);

        const char* pA = lds + buf * 16384;
        const char* pB = pA + 8192;
        bf16x8 af[4], bb[2];
#pragma unroll
        for (int m = 0; m < 4; m++) {
            int r = wr * 64 + m * 16 + l15;
            af[m] = *(const bf16x8*)(pA + r * 64 + ((g * 16) ^ (((r >> 1) & 3) << 4)));
        }
#pragma unroll
        for (int n = 0; n < 2; n++) {
            int r = wc * 32 + n * 16 + l15;
            bb[n] = *(const bf16x8*)(pB + r * 64 + ((g * 16) ^ (((r >> 1) & 3) << 4)));
        }
        __builtin_amdgcn_s_setprio(1);
#pragma unroll
        for (int m = 0; m < 4; m++)
#pragma unroll
            for (int n = 0; n < 2; n++)
                acc[m][n] = __builtin_amdgcn_mfma_f32_16x16x32_bf16(af[m], bb[n],
                                                                    acc[m][n], 0, 0, 0);
        __builtin_amdgcn_s_setprio(0);
        buf = (buf + 1) % 3;
    }

#pragma unroll
    for (int m = 0; m < 4; m++)
#pragma unroll
        for (int n = 0; n < 2; n++) {
            const int col = n0 + wc * 32 + n * 16 + l15;
            const float bv = bias[col];
#pragma unroll
            for (int rr = 0; rr < 4; rr++) {
                const int row = m0 + wr * 64 + m * 16 + g * 4 + rr;
                const long idx = (long)row * N + col;
                float val = acc[m][n][rr] + bv;
                if (EPI == 0) {
                    ((bf16_t*)Cv)[idx] = (bf16_t)val;
                } else if (EPI == 1) {
                    ((float*)Cv)[idx] = res[idx] + val;
                } else {
                    float ge = val / (1.f + __expf(-1.702f * val));
                    ((bf16_t*)Cv)[idx] = (bf16_t)ge;
                }
            }
        }
}

// ---------------- Flash attention v3: no-max softmax (unchanged) ----------------
__global__ __launch_bounds__(256) void attn_kernel(const bf16_t* __restrict__ Qd,
                                                   const bf16_t* __restrict__ Kd,
                                                   const bf16_t* __restrict__ Vt,
                                                   const int* __restrict__ cu,
                                                   int ncu,
                                                   bf16_t* __restrict__ out) {
    __shared__ bf16_t lK[64 * 104];
    __shared__ bf16_t lV[96 * 64];
    __shared__ bf16_t lP[4 * 16 * 72];

    const int tid = threadIdx.x;
    const int lane = tid & 63;
    const int l15 = lane & 15;
    const int g = lane >> 4;
    const int wid = tid >> 6;
    const int h = blockIdx.y;
    const int q0 = blockIdx.x * 64;

    int sseg = 0;
    for (int j = 1; j < ncu - 1; j++) if (q0 >= cu[j]) sseg = j;
    const int kbeg = cu[sseg], kend = cu[sseg + 1];

    bf16x8 aq[3];
    {
        const bf16_t* qp = Qd + ((long)h * NTOK + q0 + wid * 16 + l15) * 96;
#pragma unroll
        for (int ks = 0; ks < 3; ks++)
            aq[ks] = *(const bf16x8*)(qp + ks * 32 + g * 8);
    }

    for (int c = tid; c < 16 * 8; c += 256) {
        int d = 80 + c / 8, a = c % 8;
        bf16x8 v;
#pragma unroll
        for (int j = 0; j < 8; j++) v[j] = (d == 80) ? (bf16_t)1.f : (bf16_t)0.f;
        *(bf16x8*)((char*)lV + d * 128 + ((a * 16) ^ ((d & 7) << 4))) = v;
    }

    f32x4 o[6];
#pragma unroll
    for (int n = 0; n < 6; n++) o[n] = (f32x4){0.f, 0.f, 0.f, 0.f};

    bf16x8 rK[3], rV[3];
    auto ldK = [&](int kt) {
#pragma unroll
        for (int i = 0; i < 3; i++) {
            int c = tid + i * 256;
            int row = c / 12, c16 = c % 12;
            rK[i] = *(const bf16x8*)(Kd + ((long)h * NTOK + kt + row) * 96 + c16 * 8);
        }
    };
    auto ldV = [&](int kt) {
#pragma unroll
        for (int i = 0; i < 3; i++) {
            int c = tid + i * 256;
            if (c < 640) {
                int d = c / 8, a = c % 8;
                rV[i] = *(const bf16x8*)(Vt + ((long)h * HDIM + d) * NTOK + kt + a * 8);
            }
        }
    };
    auto wrKV = [&]() {
#pragma unroll
        for (int i = 0; i < 3; i++) {
            int c = tid + i * 256;
            int row = c / 12, c16 = c % 12;
            *(bf16x8*)(lK + row * 104 + c16 * 8) = rK[i];
        }
#pragma unroll
        for (int i = 0; i < 3; i++) {
            int c = tid + i * 256;
            if (c < 640) {
                int d = c / 8, a = c % 8;
                *(bf16x8*)((char*)lV + d * 128 + ((a * 16) ^ ((d & 7) << 4))) = rV[i];
            }
        }
    };

    ldK(kbeg); ldV(kbeg);
    wrKV();
    __syncthreads();

    for (int kt = kbeg; kt < kend; kt += 64) {
        const bool more = (kt + 64 < kend);
        if (more) { ldK(kt + 64); ldV(kt + 64); }

        f32x4 s[4];
#pragma unroll
        for (int n = 0; n < 4; n++) s[n] = (f32x4){0.f, 0.f, 0.f, 0.f};
#pragma unroll
        for (int n = 0; n < 4; n++)
#pragma unroll
            for (int ks = 0; ks < 3; ks++) {
                bf16x8 kf = *(const bf16x8*)(lK + (n * 16 + l15) * 104 + ks * 32 + g * 8);
                s[n] = __builtin_amdgcn_mfma_f32_16x16x32_bf16(aq[ks], kf, s[n], 0, 0, 0);
            }

#pragma unroll
        for (int n = 0; n < 4; n++)
#pragma unroll
            for (int r = 0; r < 4; r++)
                lP[wid * 1152 + (g * 4 + r) * 72 + n * 16 + l15] = (bf16_t)exp2f(s[n][r]);

        asm volatile("s_waitcnt lgkmcnt(0)" ::: "memory");
        bf16x8 pa[2];
#pragma unroll
        for (int ks = 0; ks < 2; ks++)
            pa[ks] = *(const bf16x8*)(lP + wid * 1152 + l15 * 72 + ks * 32 + g * 8);
#pragma unroll
        for (int n = 0; n < 6; n++)
#pragma unroll
            for (int ks = 0; ks < 2; ks++) {
                int rv = n * 16 + l15;
                bf16x8 vb = *(const bf16x8*)((char*)lV + rv * 128 +
                                             ((ks * 64 + g * 16) ^ ((rv & 7) << 4)));
                o[n] = __builtin_amdgcn_mfma_f32_16x16x32_bf16(pa[ks], vb, o[n], 0, 0, 0);
            }
        __syncthreads();
        if (more) wrKV();
        __syncthreads();
    }

    float lI[4];
#pragma unroll
    for (int r = 0; r < 4; r++) lI[r] = __shfl(o[5][r], lane & 48, 64);

#pragma unroll
    for (int n = 0; n < 5; n++)
#pragma unroll
        for (int r = 0; r < 4; r++) {
            int row = q0 + wid * 16 + g * 4 + r;
            out[(long)row * DIM + h * HDIM + n * 16 + l15] = (bf16_t)(o[n][r] / lI[r]);
        }
}

// ---------------- launch ----------------
extern "C" void kernel_launch(void* const* d_in, const int* in_sizes, int n_in,
                              void* d_out, int out_size, void* d_ws, size_t ws_size,
                              hipStream_t stream) {
    const float* hidden = (const float*)d_in[0];
    const float* rot    = (const float*)d_in[1];
    const int*   cu     = (const int*)d_in[2];
    const float* n1w    = (const float*)d_in[3];
    const float* n1b    = (const float*)d_in[4];
    const float* n2w    = (const float*)d_in[5];
    const float* n2b    = (const float*)d_in[6];
    const float* qkv_w  = (const float*)d_in[7];
    const float* qkv_b  = (const float*)d_in[8];
    const float* proj_w = (const float*)d_in[9];
    const float* proj_b = (const float*)d_in[10];
    const float* fc1_w  = (const float*)d_in[11];
    const float* fc1_b  = (const float*)d_in[12];
    const float* fc2_w  = (const float*)d_in[13];
    const float* fc2_b  = (const float*)d_in[14];
    float* outp = (float*)d_out;

    char* ws = (char*)d_ws;
    bf16_t* w2   = (bf16_t*)(ws);                  // [0,13.1M)        cvt->FC2
    bf16_t* w1   = (bf16_t*)(ws + 13107200);       // [13.1M,26.2M)    cvt->FC1
    bf16_t* wp   = (bf16_t*)(ws + 26214400);       // [26.2M,29.5M)    cvt->proj
    bf16_t* wq   = (bf16_t*)(ws + 29491200);       // [29.5M,39.3M)    cvt->QKV
    bf16_t* xln  = (bf16_t*)(ws + 39321600);       // [39.3M,49.8M)    LN1->QKV, LN2->FC1
    bf16_t* qkvb = (bf16_t*)(ws + 49807360);       // [49.8M,81.3M)    QKV->prep
    bf16_t* Qd   = (bf16_t*)(ws + 81264640);       // [81.3M,93.8M)    prep->attn
    bf16_t* Kd   = (bf16_t*)(ws + 93847552);       // [93.8M,106.4M)   prep->attn
    bf16_t* Vt   = (bf16_t*)(ws + 106430464);      // [106.4M,116.9M)  prep->attn
    bf16_t* attno= (bf16_t*)(ws + 116916224);      // [116.9M,127.4M)  attn->proj
    bf16_t* act  = (bf16_t*)(ws + 49807360);       // [49.8M,91.75M)   FC1->FC2 (qkvb/Qd dead)
    // h (f32) lives in d_out: proj writes (EPI1), LN2 reads, FC2 (EPI1) accumulates.

    int ncu = in_sizes[2];

    cvt_all<<<2048, 256, 0, stream>>>(fc2_w, fc1_w, proj_w, qkv_w,
                                      w2, w1, wp, wq,
                                      DIM * MLP, MLP * DIM, DIM * DIM, QKV_N * DIM);

    ln_kernel<<<NTOK, 256, 0, stream>>>(hidden, n1w, n1b, xln);
    // QKV: 4096x3840x1280 -> 15x32 = 480 blocks (gemmU, BN=256), NT=40
    gemmU<0><<<dim3(QKV_N / 256, NTOK / 128, 1), 512, 0, stream>>>(
        xln, wq, qkv_b, qkvb, NTOK, QKV_N, DIM);
    prep_kernel<<<dim3(NTOK / 64, NHEADS), 256, 0, stream>>>(qkvb, rot, Qd, Kd, Vt);
    attn_kernel<<<dim3(NTOK / 64, NHEADS), 256, 0, stream>>>(Qd, Kd, Vt, cu, ncu, attno);
    // proj: 4096x1280x1280 -> 10x32 = 320 blocks (gemmS), NT=40
    gemmS<1><<<dim3(DIM / 128, NTOK / 128, 1), 512, 0, stream>>>(
        attno, wp, proj_b, hidden, outp, NTOK, DIM, DIM, DIM);
    ln_kernel<<<NTOK, 256, 0, stream>>>(outp, n2w, n2b, xln);
    // FC1: 4096x5120x1280 -> 40x32 = 1280 blocks (gemmS, measured best 85us), NT=40
    gemmS<2><<<dim3(MLP / 128, NTOK / 128, 1), 512, 0, stream>>>(
        xln, w1, fc1_b, nullptr, act, NTOK, MLP, DIM, DIM);
    // FC2: 4096x1280x5120 -> 10x32 = 320 blocks (gemmS), NT=160
    gemmS<1><<<dim3(DIM / 128, NTOK / 128, 1), 512, 0, stream>>>(
        act, w2, fc2_b, outp, outp, NTOK, DIM, MLP, MLP);
}

// Round 20
// 320.894 us; speedup vs baseline: 1.0025x; 1.0025x over previous
//
#include <hip/hip_runtime.h>
#include <hip/hip_bf16.h>

// Qwen2VL vision block, MI355X gfx950.
// R20: R19 config (per-dispatch measured best: QKV gemmU, FC1/proj/FC2 gemmS)
//      + vectorized LayerNorm (320 thr, float4 loads, packed bf16x4 stores).

typedef __bf16 bf16_t;
typedef bf16_t bf16x8 __attribute__((ext_vector_type(8)));
typedef bf16_t bf16x4 __attribute__((ext_vector_type(4)));
typedef float f32x4 __attribute__((ext_vector_type(4)));

#define DIM 1280
#define NHEADS 16
#define HDIM 80
#define MLP 5120
#define NTOK 4096
#define QKV_N 3840

#define GLOAD_LDS16(gp, lp)                                                          \
    __builtin_amdgcn_global_load_lds((const __attribute__((address_space(1))) void*)(gp), \
                                     (__attribute__((address_space(3))) void*)(lp), 16, 0, 0)

// ---------------- fused fp32 -> bf16 conversion of all 4 weight tensors ------
__global__ void cvt_all(const float* __restrict__ s0, const float* __restrict__ s1,
                        const float* __restrict__ s2, const float* __restrict__ s3,
                        bf16_t* __restrict__ d0, bf16_t* __restrict__ d1,
                        bf16_t* __restrict__ d2, bf16_t* __restrict__ d3,
                        int n0, int n1, int n2, int n3) {
    int q0 = n0 >> 2, q1 = n1 >> 2, q2 = n2 >> 2, q3 = n3 >> 2;
    int total = q0 + q1 + q2 + q3;
    for (int i = blockIdx.x * blockDim.x + threadIdx.x; i < total;
         i += gridDim.x * blockDim.x) {
        const float* src;
        bf16_t* dst;
        int j = i;
        if (j < q0) { src = s0; dst = d0; }
        else if ((j -= q0) < q1) { src = s1; dst = d1; }
        else if ((j -= q1) < q2) { src = s2; dst = d2; }
        else { j -= q2; src = s3; dst = d3; }
        float4 v = ((const float4*)src)[j];
        bf16x4 o;
        o[0] = (bf16_t)v.x; o[1] = (bf16_t)v.y; o[2] = (bf16_t)v.z; o[3] = (bf16_t)v.w;
        *(bf16x4*)(dst + j * 4) = o;
    }
}

// ---------------- LayerNorm (fp32 in, bf16 out), 320 thr, vectorized ---------
__global__ __launch_bounds__(320) void ln_kernel(const float* __restrict__ x,
                                                 const float* __restrict__ w,
                                                 const float* __restrict__ b,
                                                 bf16_t* __restrict__ out) {
    const int row = blockIdx.x;
    const int t = threadIdx.x;              // 0..319, each owns 4 floats
    float4 v = ((const float4*)(x + (long)row * DIM))[t];
    float s = v.x + v.y + v.z + v.w;
    float ss = v.x * v.x + v.y * v.y + v.z * v.z + v.w * v.w;
#pragma unroll
    for (int off = 32; off > 0; off >>= 1) {
        s += __shfl_xor(s, off, 64);
        ss += __shfl_xor(ss, off, 64);
    }
    __shared__ float red[10];
    int wid = t >> 6;  // 0..4
    if ((t & 63) == 0) { red[wid] = s; red[wid + 5] = ss; }
    __syncthreads();
    s = red[0] + red[1] + red[2] + red[3] + red[4];
    ss = red[5] + red[6] + red[7] + red[8] + red[9];
    float mean = s * (1.f / DIM);
    float var = ss * (1.f / DIM) - mean * mean;
    float rstd = rsqrtf(var + 1e-6f);
    float4 wv = ((const float4*)w)[t];
    float4 bv = ((const float4*)b)[t];
    bf16x4 o;
    o[0] = (bf16_t)((v.x - mean) * rstd * wv.x + bv.x);
    o[1] = (bf16_t)((v.y - mean) * rstd * wv.y + bv.y);
    o[2] = (bf16_t)((v.z - mean) * rstd * wv.z + bv.z);
    o[3] = (bf16_t)((v.w - mean) * rstd * wv.w + bv.w);
    *(bf16x4*)(out + (long)row * DIM + t * 4) = o;
}

// ---------------- prep: fused RoPE + layouts; Q pre-scaled by scale*log2e ----
__global__ __launch_bounds__(256) void prep_kernel(const bf16_t* __restrict__ qkv,
                                                   const float* __restrict__ rot,
                                                   bf16_t* __restrict__ Qd,
                                                   bf16_t* __restrict__ Kd,
                                                   bf16_t* __restrict__ Vt) {
    const float SCL = 0.11180339887498949f * 1.4426950408889634f;  // 1/sqrt(80)*log2(e)
    __shared__ bf16_t tv[64 * 88];
    const int tid = threadIdx.x;
    const int t0 = blockIdx.x * 64;
    const int h = blockIdx.y;

    for (int c = tid; c < 64 * 10; c += 256) {
        int tl = c / 10, a = c % 10;
        bf16x8 v = *(const bf16x8*)(qkv + (long)(t0 + tl) * QKV_N + 2 * DIM + h * HDIM + a * 8);
        *(bf16x8*)(tv + tl * 88 + a * 8) = v;
    }

    for (int c = tid; c < 64 * 10; c += 256) {
        int tl = c / 10, a = c % 10;
        long gq = (long)(t0 + tl) * QKV_N + h * HDIM + a * 4;
        bf16x4 q1 = *(const bf16x4*)(qkv + gq);
        bf16x4 q2 = *(const bf16x4*)(qkv + gq + 40);
        bf16x4 k1 = *(const bf16x4*)(qkv + gq + DIM);
        bf16x4 k2 = *(const bf16x4*)(qkv + gq + DIM + 40);
        float4 rv = *(const float4*)(rot + (long)(t0 + tl) * 40 + a * 4);
        float rr[4] = {rv.x, rv.y, rv.z, rv.w};
        bf16x4 oq1, oq2, ok1, ok2;
#pragma unroll
        for (int j = 0; j < 4; j++) {
            float c_, s_;
            __sincosf(rr[j], &s_, &c_);
            float x1 = (float)q1[j], x2 = (float)q2[j];
            oq1[j] = (bf16_t)((x1 * c_ - x2 * s_) * SCL);
            oq2[j] = (bf16_t)((x2 * c_ + x1 * s_) * SCL);
            x1 = (float)k1[j]; x2 = (float)k2[j];
            ok1[j] = (bf16_t)(x1 * c_ - x2 * s_);
            ok2[j] = (bf16_t)(x2 * c_ + x1 * s_);
        }
        long o = ((long)h * NTOK + t0 + tl) * 96 + a * 4;
        *(bf16x4*)(Qd + o) = oq1;
        *(bf16x4*)(Qd + o + 40) = oq2;
        *(bf16x4*)(Kd + o) = ok1;
        *(bf16x4*)(Kd + o + 40) = ok2;
    }
    {
        bf16x8 z;
#pragma unroll
        for (int j = 0; j < 8; j++) z[j] = (bf16_t)0.f;
        for (int c = tid; c < 64 * 2; c += 256) {
            int tl = c / 2, a = c % 2;
            long o = ((long)h * NTOK + t0 + tl) * 96 + 80 + a * 8;
            *(bf16x8*)(Qd + o) = z;
            *(bf16x8*)(Kd + o) = z;
        }
    }
    __syncthreads();

    for (int c = tid; c < 80 * 8; c += 256) {
        int d = c / 8, tc = c % 8;
        bf16x8 v;
#pragma unroll
        for (int j = 0; j < 8; j++) v[j] = tv[(tc * 8 + j) * 88 + d];
        *(bf16x8*)(Vt + ((long)h * HDIM + d) * NTOK + t0 + tc * 8) = v;
    }
}

// ---------------- gemmU: 128(M) x 256(N), 8 waves, per-wave 64x64 (QKV) ------
template <int EPI>
__global__ __launch_bounds__(512, 2) void gemmU(const bf16_t* __restrict__ A,
                                                const bf16_t* __restrict__ B,
                                                const float* __restrict__ bias,
                                                void* __restrict__ Cv,
                                                int M, int N, int K) {
    __shared__ char lds[3 * 24576];  // 72 KB
    const int tid = threadIdx.x;
    const int lane = tid & 63;
    const int l15 = lane & 15;
    const int g = lane >> 4;
    const int wid = tid >> 6;
    const int wr = wid >> 2;
    const int wc = wid & 3;

    const int nx = gridDim.x;
    const int id = blockIdx.y * nx + blockIdx.x;
    const int cpx = (nx * gridDim.y) >> 3;
    const int sid = (id & 7) * cpx + (id >> 3);
    const int m0 = (sid / nx) * 128;
    const int n0 = (sid % nx) * 256;
    const int NT = K >> 5;

    const int soff = tid * 16;
    const int srow = soff >> 6;
    const int scb = (soff & 63) ^ (((srow >> 1) & 3) << 4);
    const bf16_t* g0 = A + (long)(m0 + srow) * K + (scb >> 1);
    const bf16_t* g1 = B + (long)(n0 + srow) * K + (scb >> 1);
    const int srow2 = 128 + srow;
    const int scb2 = (soff & 63) ^ (((srow2 >> 1) & 3) << 4);
    const bf16_t* g2 = B + (long)(n0 + srow2) * K + (scb2 >> 1);
    const int l0 = wid * 1024;
    const int l1 = 8192 + wid * 1024;
    const int l2 = 16384 + wid * 1024;

    f32x4 acc[4][4];
#pragma unroll
    for (int i = 0; i < 4; i++)
#pragma unroll
        for (int j = 0; j < 4; j++) acc[i][j] = (f32x4){0.f, 0.f, 0.f, 0.f};

    auto stage = [&](int buf, int t) {
        char* sb = lds + buf * 24576;
        GLOAD_LDS16(g0 + t * 32, sb + l0);
        GLOAD_LDS16(g1 + t * 32, sb + l1);
        GLOAD_LDS16(g2 + t * 32, sb + l2);
    };

    stage(0, 0);
    stage(1, 1);

    int buf = 0;
    for (int t = 0; t < NT; ++t) {
        if (t < NT - 1)
            asm volatile("s_waitcnt vmcnt(3)\n\ts_barrier" ::: "memory");
        else
            asm volatile("s_waitcnt vmcnt(0)\n\ts_barrier" ::: "memory");
        if (t + 2 < NT) stage((buf + 2) % 3, t + 2);

        const char* pA = lds + buf * 24576;
        const char* pB = pA + 8192;
        bf16x8 af[4], bb[4];
#pragma unroll
        for (int m = 0; m < 4; m++) {
            int r = wr * 64 + m * 16 + l15;
            af[m] = *(const bf16x8*)(pA + r * 64 + ((g * 16) ^ (((r >> 1) & 3) << 4)));
        }
#pragma unroll
        for (int n = 0; n < 4; n++) {
            int r = wc * 64 + n * 16 + l15;
            bb[n] = *(const bf16x8*)(pB + r * 64 + ((g * 16) ^ (((r >> 1) & 3) << 4)));
        }
        __builtin_amdgcn_s_setprio(1);
#pragma unroll
        for (int m = 0; m < 4; m++)
#pragma unroll
            for (int n = 0; n < 4; n++)
                acc[m][n] = __builtin_amdgcn_mfma_f32_16x16x32_bf16(af[m], bb[n],
                                                                    acc[m][n], 0, 0, 0);
        __builtin_amdgcn_s_setprio(0);
        buf = (buf + 1) % 3;
    }

#pragma unroll
    for (int m = 0; m < 4; m++)
#pragma unroll
        for (int n = 0; n < 4; n++) {
            const int col = n0 + wc * 64 + n * 16 + l15;
            const float bv = bias[col];
#pragma unroll
            for (int rr = 0; rr < 4; rr++) {
                const int row = m0 + wr * 64 + m * 16 + g * 4 + rr;
                const long idx = (long)row * N + col;
                float val = acc[m][n][rr] + bv;
                if (EPI == 0) {
                    ((bf16_t*)Cv)[idx] = (bf16_t)val;
                } else {
                    float ge = val / (1.f + __expf(-1.702f * val));
                    ((bf16_t*)Cv)[idx] = (bf16_t)ge;
                }
            }
        }
}

// ---------------- gemmS: 128x128, 8 waves 64x32, 24 waves/CU -----------------
template <int EPI>
__global__ __launch_bounds__(512, 4) void gemmS(const bf16_t* __restrict__ A,
                                                const bf16_t* __restrict__ B,
                                                const float* __restrict__ bias,
                                                const float* __restrict__ res,
                                                void* __restrict__ Cv,
                                                int M, int N, int K, int kspl) {
    __shared__ char lds[3 * 16384];  // 48 KB
    const int tid = threadIdx.x;
    const int lane = tid & 63;
    const int l15 = lane & 15;
    const int g = lane >> 4;
    const int wid = tid >> 6;
    const int wr = wid >> 2;
    const int wc = wid & 3;

    const int nx = gridDim.x;
    const int id = blockIdx.y * nx + blockIdx.x;
    const int cpx = (nx * gridDim.y) >> 3;
    const int sid = (id & 7) * cpx + (id >> 3);
    const int m0 = (sid / nx) * 128;
    const int n0 = (sid % nx) * 128;
    const int k0 = blockIdx.z * kspl;
    const int NT = kspl >> 5;

    const int soff = tid * 16;
    const int srow = soff >> 6;
    const int scb = (soff & 63) ^ (((srow >> 1) & 3) << 4);
    const bf16_t* gA = A + (long)(m0 + srow) * K + k0 + (scb >> 1);
    const bf16_t* gB = B + (long)(n0 + srow) * K + k0 + (scb >> 1);
    const int lAo = wid * 1024;
    const int lBo = 8192 + wid * 1024;

    f32x4 acc[4][2];
#pragma unroll
    for (int i = 0; i < 4; i++)
#pragma unroll
        for (int j = 0; j < 2; j++) acc[i][j] = (f32x4){0.f, 0.f, 0.f, 0.f};

    auto stage = [&](int buf, int t) {
        char* sb = lds + buf * 16384;
        GLOAD_LDS16(gA + t * 32, sb + lAo);
        GLOAD_LDS16(gB + t * 32, sb + lBo);
    };

    stage(0, 0);
    stage(1, 1);

    int buf = 0;
    for (int t = 0; t < NT; ++t) {
        if (t < NT - 1)
            asm volatile("s_waitcnt vmcnt(2)\n\ts_barrier" ::: "memory");
        else
            asm volatile("s_waitcnt vmcnt(0)\n\ts_barrier" ::: "memory");
        if (t + 2 < NT) stage((buf + 2) % 3, t + 2);

        const char* pA = lds + buf * 16384;
        const char* pB = pA + 8192;
        bf16x8 af[4], bb[2];
#pragma unroll
        for (int m = 0; m < 4; m++) {
            int r = wr * 64 + m * 16 + l15;
            af[m] = *(const bf16x8*)(pA + r * 64 + ((g * 16) ^ (((r >> 1) & 3) << 4)));
        }
#pragma unroll
        for (int n = 0; n < 2; n++) {
            int r = wc * 32 + n * 16 + l15;
            bb[n] = *(const bf16x8*)(pB + r * 64 + ((g * 16) ^ (((r >> 1) & 3) << 4)));
        }
        __builtin_amdgcn_s_setprio(1);
#pragma unroll
        for (int m = 0; m < 4; m++)
#pragma unroll
            for (int n = 0; n < 2; n++)
                acc[m][n] = __builtin_amdgcn_mfma_f32_16x16x32_bf16(af[m], bb[n],
                                                                    acc[m][n], 0, 0, 0);
        __builtin_amdgcn_s_setprio(0);
        buf = (buf + 1) % 3;
    }

#pragma unroll
    for (int m = 0; m < 4; m++)
#pragma unroll
        for (int n = 0; n < 2; n++) {
            const int col = n0 + wc * 32 + n * 16 + l15;
            const float bv = bias[col];
#pragma unroll
            for (int rr = 0; rr < 4; rr++) {
                const int row = m0 + wr * 64 + m * 16 + g * 4 + rr;
                const long idx = (long)row * N + col;
                float val = acc[m][n][rr] + bv;
                if (EPI == 0) {
                    ((bf16_t*)Cv)[idx] = (bf16_t)val;
                } else if (EPI == 1) {
                    ((float*)Cv)[idx] = res[idx] + val;
                } else {
                    float ge = val / (1.f + __expf(-1.702f * val));
                    ((bf16_t*)Cv)[idx] = (bf16_t)ge;
                }
            }
        }
}

// ---------------- Flash attention v3: no-max softmax (unchanged) ----------------
__global__ __launch_bounds__(256) void attn_kernel(const bf16_t* __restrict__ Qd,
                                                   const bf16_t* __restrict__ Kd,
                                                   const bf16_t* __restrict__ Vt,
                                                   const int* __restrict__ cu,
                                                   int ncu,
                                                   bf16_t* __restrict__ out) {
    __shared__ bf16_t lK[64 * 104];
    __shared__ bf16_t lV[96 * 64];
    __shared__ bf16_t lP[4 * 16 * 72];

    const int tid = threadIdx.x;
    const int lane = tid & 63;
    const int l15 = lane & 15;
    const int g = lane >> 4;
    const int wid = tid >> 6;
    const int h = blockIdx.y;
    const int q0 = blockIdx.x * 64;

    int sseg = 0;
    for (int j = 1; j < ncu - 1; j++) if (q0 >= cu[j]) sseg = j;
    const int kbeg = cu[sseg], kend = cu[sseg + 1];

    bf16x8 aq[3];
    {
        const bf16_t* qp = Qd + ((long)h * NTOK + q0 + wid * 16 + l15) * 96;
#pragma unroll
        for (int ks = 0; ks < 3; ks++)
            aq[ks] = *(const bf16x8*)(qp + ks * 32 + g * 8);
    }

    for (int c = tid; c < 16 * 8; c += 256) {
        int d = 80 + c / 8, a = c % 8;
        bf16x8 v;
#pragma unroll
        for (int j = 0; j < 8; j++) v[j] = (d == 80) ? (bf16_t)1.f : (bf16_t)0.f;
        *(bf16x8*)((char*)lV + d * 128 + ((a * 16) ^ ((d & 7) << 4))) = v;
    }

    f32x4 o[6];
#pragma unroll
    for (int n = 0; n < 6; n++) o[n] = (f32x4){0.f, 0.f, 0.f, 0.f};

    bf16x8 rK[3], rV[3];
    auto ldK = [&](int kt) {
#pragma unroll
        for (int i = 0; i < 3; i++) {
            int c = tid + i * 256;
            int row = c / 12, c16 = c % 12;
            rK[i] = *(const bf16x8*)(Kd + ((long)h * NTOK + kt + row) * 96 + c16 * 8);
        }
    };
    auto ldV = [&](int kt) {
#pragma unroll
        for (int i = 0; i < 3; i++) {
            int c = tid + i * 256;
            if (c < 640) {
                int d = c / 8, a = c % 8;
                rV[i] = *(const bf16x8*)(Vt + ((long)h * HDIM + d) * NTOK + kt + a * 8);
            }
        }
    };
    auto wrKV = [&]() {
#pragma unroll
        for (int i = 0; i < 3; i++) {
            int c = tid + i * 256;
            int row = c / 12, c16 = c % 12;
            *(bf16x8*)(lK + row * 104 + c16 * 8) = rK[i];
        }
#pragma unroll
        for (int i = 0; i < 3; i++) {
            int c = tid + i * 256;
            if (c < 640) {
                int d = c / 8, a = c % 8;
                *(bf16x8*)((char*)lV + d * 128 + ((a * 16) ^ ((d & 7) << 4))) = rV[i];
            }
        }
    };

    ldK(kbeg); ldV(kbeg);
    wrKV();
    __syncthreads();

    for (int kt = kbeg; kt < kend; kt += 64) {
        const bool more = (kt + 64 < kend);
        if (more) { ldK(kt + 64); ldV(kt + 64); }

        f32x4 s[4];
#pragma unroll
        for (int n = 0; n < 4; n++) s[n] = (f32x4){0.f, 0.f, 0.f, 0.f};
#pragma unroll
        for (int n = 0; n < 4; n++)
#pragma unroll
            for (int ks = 0; ks < 3; ks++) {
                bf16x8 kf = *(const bf16x8*)(lK + (n * 16 + l15) * 104 + ks * 32 + g * 8);
                s[n] = __builtin_amdgcn_mfma_f32_16x16x32_bf16(aq[ks], kf, s[n], 0, 0, 0);
            }

#pragma unroll
        for (int n = 0; n < 4; n++)
#pragma unroll
            for (int r = 0; r < 4; r++)
                lP[wid * 1152 + (g * 4 + r) * 72 + n * 16 + l15] = (bf16_t)exp2f(s[n][r]);

        asm volatile("s_waitcnt lgkmcnt(0)" ::: "memory");
        bf16x8 pa[2];
#pragma unroll
        for (int ks = 0; ks < 2; ks++)
            pa[ks] = *(const bf16x8*)(lP + wid * 1152 + l15 * 72 + ks * 32 + g * 8);
#pragma unroll
        for (int n = 0; n < 6; n++)
#pragma unroll
            for (int ks = 0; ks < 2; ks++) {
                int rv = n * 16 + l15;
                bf16x8 vb = *(const bf16x8*)((char*)lV + rv * 128 +
                                             ((ks * 64 + g * 16) ^ ((rv & 7) << 4)));
                o[n] = __builtin_amdgcn_mfma_f32_16x16x32_bf16(pa[ks], vb, o[n], 0, 0, 0);
            }
        __syncthreads();
        if (more) wrKV();
        __syncthreads();
    }

    float lI[4];
#pragma unroll
    for (int r = 0; r < 4; r++) lI[r] = __shfl(o[5][r], lane & 48, 64);

#pragma unroll
    for (int n = 0; n < 5; n++)
#pragma unroll
        for (int r = 0; r < 4; r++) {
            int row = q0 + wid * 16 + g * 4 + r;
            out[(long)row * DIM + h * HDIM + n * 16 + l15] = (bf16_t)(o[n][r] / lI[r]);
        }
}

// ---------------- launch ----------------
extern "C" void kernel_launch(void* const* d_in, const int* in_sizes, int n_in,
                              void* d_out, int out_size, void* d_ws, size_t ws_size,
                              hipStream_t stream) {
    const float* hidden = (const float*)d_in[0];
    const float* rot    = (const float*)d_in[1];
    const int*   cu     = (const int*)d_in[2];
    const float* n1w    = (const float*)d_in[3];
    const float* n1b    = (const float*)d_in[4];
    const float* n2w    = (const float*)d_in[5];
    const float* n2b    = (const float*)d_in[6];
    const float* qkv_w  = (const float*)d_in[7];
    const float* qkv_b  = (const float*)d_in[8];
    const float* proj_w = (const float*)d_in[9];
    const float* proj_b = (const float*)d_in[10];
    const float* fc1_w  = (const float*)d_in[11];
    const float* fc1_b  = (const float*)d_in[12];
    const float* fc2_w  = (const float*)d_in[13];
    const float* fc2_b  = (const float*)d_in[14];
    float* outp = (float*)d_out;

    char* ws = (char*)d_ws;
    bf16_t* w2   = (bf16_t*)(ws);                  // [0,13.1M)        cvt->FC2
    bf16_t* w1   = (bf16_t*)(ws + 13107200);       // [13.1M,26.2M)    cvt->FC1
    bf16_t* wp   = (bf16_t*)(ws + 26214400);       // [26.2M,29.5M)    cvt->proj
    bf16_t* wq   = (bf16_t*)(ws + 29491200);       // [29.5M,39.3M)    cvt->QKV
    bf16_t* xln  = (bf16_t*)(ws + 39321600);       // [39.3M,49.8M)    LN1->QKV, LN2->FC1
    bf16_t* qkvb = (bf16_t*)(ws + 49807360);       // [49.8M,81.3M)    QKV->prep
    bf16_t* Qd   = (bf16_t*)(ws + 81264640);       // [81.3M,93.8M)    prep->attn
    bf16_t* Kd   = (bf16_t*)(ws + 93847552);       // [93.8M,106.4M)   prep->attn
    bf16_t* Vt   = (bf16_t*)(ws + 106430464);      // [106.4M,116.9M)  prep->attn
    bf16_t* attno= (bf16_t*)(ws + 116916224);      // [116.9M,127.4M)  attn->proj
    bf16_t* act  = (bf16_t*)(ws + 49807360);       // [49.8M,91.75M)   FC1->FC2 (qkvb/Qd dead)
    // h (f32) lives in d_out: proj writes (EPI1), LN2 reads, FC2 (EPI1) accumulates.

    int ncu = in_sizes[2];

    cvt_all<<<2048, 256, 0, stream>>>(fc2_w, fc1_w, proj_w, qkv_w,
                                      w2, w1, wp, wq,
                                      DIM * MLP, MLP * DIM, DIM * DIM, QKV_N * DIM);

    ln_kernel<<<NTOK, 320, 0, stream>>>(hidden, n1w, n1b, xln);
    // QKV: 4096x3840x1280 -> 15x32 = 480 blocks (gemmU, BN=256), NT=40
    gemmU<0><<<dim3(QKV_N / 256, NTOK / 128, 1), 512, 0, stream>>>(
        xln, wq, qkv_b, qkvb, NTOK, QKV_N, DIM);
    prep_kernel<<<dim3(NTOK / 64, NHEADS), 256, 0, stream>>>(qkvb, rot, Qd, Kd, Vt);
    attn_kernel<<<dim3(NTOK / 64, NHEADS), 256, 0, stream>>>(Qd, Kd, Vt, cu, ncu, attno);
    // proj: 4096x1280x1280 -> 10x32 = 320 blocks (gemmS), NT=40
    gemmS<1><<<dim3(DIM / 128, NTOK / 128, 1), 512, 0, stream>>>(
        attno, wp, proj_b, hidden, outp, NTOK, DIM, DIM, DIM);
    ln_kernel<<<NTOK, 320, 0, stream>>>(outp, n2w, n2b, xln);
    // FC1: 4096x5120x1280 -> 40x32 = 1280 blocks (gemmS, measured best 85us), NT=40
    gemmS<2><<<dim3(MLP / 128, NTOK / 128, 1), 512, 0, stream>>>(
        xln, w1, fc1_b, nullptr, act, NTOK, MLP, DIM, DIM);
    // FC2: 4096x1280x5120 -> 10x32 = 320 blocks (gemmS), NT=160
    gemmS<1><<<dim3(DIM / 128, NTOK / 128, 1), 512, 0, stream>>>(
        act, w2, fc2_b, outp, outp, NTOK, DIM, MLP, MLP);
}